// Round 5
// baseline (717.658 us; speedup 1.0000x reference)
//
#include <hip/hip_runtime.h>
#include <hip/hip_bf16.h>

// Problem: x [32768,512] fp32, centroids [8192,512] fp32
#define N_ROWS 32768
#define DIM    512
#define K_CENT 8192

// Output (flat fp32): x_q [N*D] | loss [1] | indices-as-float [N]
#define LOSS_OFF 16777216u
#define IDX_OFF  16777217u

// Scratch carved from the x_q region of d_out (xh/ch always; cnorm/cand only
// when d_ws is too small for them):
#define XH_OFF_B   0u
#define CH_OFF_B   33554432u
#define CN_OFF_B   41943040u
#define CAND_OFF_B 41975808u

#define CAND_BYTES 4194304u
#define CN_BYTES   32768u

#define BM 128
#define BN 128
#define BK 64
#define KQ 2048              // columns per blockIdx.y quarter
#define NKT (KQ / BN)        // 16
#define NQ  (K_CENT / KQ)    // 4
#define NSTEP (NKT * 8)      // 128 pipeline steps (8 per kt)

typedef __bf16 bf16x8 __attribute__((ext_vector_type(8)));
typedef float  f32x4  __attribute__((ext_vector_type(4)));

__device__ __forceinline__ unsigned short f2bf(float f) {
    unsigned u = __float_as_uint(f);
    return (unsigned short)((u + 0x7fffu + ((u >> 16) & 1u)) >> 16);
}

// Async global->LDS, 16B per lane. LDS dest = wave-uniform base + lane*16;
// GLOBAL src is per-lane.
__device__ __forceinline__ void glds16(void* lds, const void* g) {
    __builtin_amdgcn_global_load_lds(
        (const __attribute__((address_space(1))) unsigned*)g,
        (__attribute__((address_space(3))) unsigned*)lds, 16, 0, 0);
}

// compare-exchange on (d,i) pairs, lexicographic
__device__ __forceinline__ void ce(float& da, int& ia, float& db, int& ib) {
    bool sw = (db < da) || (db == da && ib < ia);
    float td = sw ? db : da; int ti = sw ? ib : ia;
    float ud = sw ? da : db; int ui = sw ? ia : ib;
    da = td; ia = ti; db = ud; ib = ui;
}
__device__ __forceinline__ void lmin(float da, int ia, float db, int ib,
                                     float& od, int& oi) {
    bool sw = (db < da) || (db == da && ib < ia);
    od = sw ? db : da; oi = sw ? ib : ia;
}

// ---------------- k0: one-shot fp32 -> bf16(hi) conversion + c_norm
__global__ void __launch_bounds__(256) convert_kernel(const float* __restrict__ x,
                                                      const float* __restrict__ c,
                                                      unsigned short* __restrict__ xh,
                                                      unsigned short* __restrict__ ch,
                                                      float* __restrict__ cnp) {
    const int wave = threadIdx.x >> 6, lane = threadIdx.x & 63;
    const int gid = blockIdx.x * 4 + wave;
    if (gid < N_ROWS) {
        const float* p = x + (size_t)gid * DIM + lane * 8;
        float4 a = *(const float4*)p, b = *(const float4*)(p + 4);
        uint4 w;
        w.x = (unsigned)f2bf(a.x) | ((unsigned)f2bf(a.y) << 16);
        w.y = (unsigned)f2bf(a.z) | ((unsigned)f2bf(a.w) << 16);
        w.z = (unsigned)f2bf(b.x) | ((unsigned)f2bf(b.y) << 16);
        w.w = (unsigned)f2bf(b.z) | ((unsigned)f2bf(b.w) << 16);
        *(uint4*)(xh + (size_t)gid * DIM + lane * 8) = w;
    } else {
        const int cr = gid - N_ROWS;
        const float* p = c + (size_t)cr * DIM + lane * 8;
        float4 a = *(const float4*)p, b = *(const float4*)(p + 4);
        uint4 w;
        w.x = (unsigned)f2bf(a.x) | ((unsigned)f2bf(a.y) << 16);
        w.y = (unsigned)f2bf(a.z) | ((unsigned)f2bf(a.w) << 16);
        w.z = (unsigned)f2bf(b.x) | ((unsigned)f2bf(b.y) << 16);
        w.w = (unsigned)f2bf(b.z) | ((unsigned)f2bf(b.w) << 16);
        *(uint4*)(ch + (size_t)cr * DIM + lane * 8) = w;
        float s = a.x*a.x + a.y*a.y + a.z*a.z + a.w*a.w
                + b.x*b.x + b.y*b.y + b.z*b.z + b.w*b.w;
#pragma unroll
        for (int off = 32; off; off >>= 1) s += __shfl_down(s, off, 64);
        if (lane == 0) cnp[cr] = s;
    }
}

// ---------------- k1: bf16 MFMA proxy GEMM, T3 double-buffered pipeline.
// grid (256, 4). BK=64, XOR bank-swizzle (round-2 hardware-proven: passed,
// 0 bank conflicts): LDS linear for global_load_lds; GLOBAL source slot
// pre-swizzled with the involution the ds_read side applies (slot ^= row&7).
// Pipeline order per step: STAGE(s+1) -> compute(s) -> vmcnt(0)+barrier.
__global__ void __launch_bounds__(256, 2) vq_main(const unsigned short* __restrict__ xh,
                                                  const unsigned short* __restrict__ ch,
                                                  const float* __restrict__ cnp,
                                                  float* __restrict__ cand) {
    __shared__ __align__(16) unsigned short xs[2][BM * BK];  // 2 x 16 KB
    __shared__ __align__(16) unsigned short cs[2][BN * BK];  // 2 x 16 KB
    __shared__ __align__(16) float cnl[KQ];                  // 8 KB
    __shared__ float sh_d[2][BM][4];                         // 4 KB
    __shared__ int   sh_i[2][BM][4];                         // 4 KB

    const int tid  = threadIdx.x;
    const int wave = tid >> 6, lane = tid & 63;
    const int wm   = wave >> 1, wk = wave & 1;
    const int lr   = lane & 15, quad = lane >> 4;
    const int nbase = blockIdx.x * BM;
    const int kc0   = blockIdx.y * KQ;

    // staging geometry: wave stages rows [wave*32,+32), 8 rows per glds16.
    // lane -> (row = lane>>3, slot = lane&7); source slot pre-swizzled.
    const int srow8 = lane >> 3;
    const int scol  = ((lane & 7) ^ srow8) * 8;
    const unsigned short* xg  = xh + (size_t)(nbase + wave * 32 + srow8) * DIM + scol;
    const unsigned short* cgb = ch + (size_t)(kc0 + wave * 32 + srow8) * DIM + scol;

    // fragment read offsets (bytes); kk toggles bit 6 (^0x40)
    int aoff[4], boff[4];
#pragma unroll
    for (int t = 0; t < 4; ++t) {
        aoff[t] = (wm * 64 + t * 16 + lr) * 128 + ((quad * 16) ^ ((lr & 7) << 4));
        boff[t] = (wk * 64 + t * 16 + lr) * 128 + ((quad * 16) ^ ((lr & 7) << 4));
    }

    float rd1[4][4], rd2[4][4];
    int   ri1[4][4], ri2[4][4];
#pragma unroll
    for (int mt = 0; mt < 4; ++mt)
#pragma unroll
        for (int r = 0; r < 4; ++r) {
            rd1[mt][r] = 1e30f; rd2[mt][r] = 1e30f;
            ri1[mt][r] = 0x7ffffff0; ri2[mt][r] = 0x7ffffff1;
        }

    // ---- prologue: c_norm quarter -> LDS, plus stage step 0
    {
        const float* cns = cnp + kc0 + wave * 512 + lane * 4;
        float* cnd = &cnl[wave * 512];
        glds16(cnd, cns);
        glds16(cnd + 256, cns + 256);
    }
    {
        unsigned short* xd = &xs[0][wave * 2048];
        unsigned short* cd = &cs[0][wave * 2048];
#pragma unroll
        for (int g = 0; g < 4; ++g) glds16(xd + g * 512, xg + g * 8 * DIM);
#pragma unroll
        for (int g = 0; g < 4; ++g) glds16(cd + g * 512, cgb + g * 8 * DIM);
    }
    asm volatile("s_waitcnt vmcnt(0)" ::: "memory");
    __builtin_amdgcn_s_barrier();

    for (int kt = 0; kt < NKT; ++kt) {
        f32x4 acc[4][4];
#pragma unroll
        for (int mt = 0; mt < 4; ++mt)
#pragma unroll
            for (int t = 0; t < 4; ++t)
                acc[mt][t] = (f32x4){0.f, 0.f, 0.f, 0.f};

        for (int dsb = 0; dsb < 8; ++dsb) {
            const int s = kt * 8 + dsb;
            // ---- stage step s+1 into the other buffer (overlaps compute)
            if (s + 1 < NSTEP) {
                const int sn  = s + 1;
                const int ktn = sn >> 3;
                const int dn  = (sn & 7) * 64;
                const int bn  = sn & 1;
                unsigned short* xd = &xs[bn][wave * 2048];
                unsigned short* cd = &cs[bn][wave * 2048];
                const unsigned short* xsrc = xg + dn;
                const unsigned short* csrc = cgb + (size_t)ktn * (BN * DIM) + dn;
#pragma unroll
                for (int g = 0; g < 4; ++g) glds16(xd + g * 512, xsrc + g * 8 * DIM);
#pragma unroll
                for (int g = 0; g < 4; ++g) glds16(cd + g * 512, csrc + g * 8 * DIM);
            }
            // ---- compute step s from buffer s&1
            const int b = s & 1;
            const char* xb = (const char*)&xs[b][0];
            const char* cb = (const char*)&cs[b][0];
#pragma unroll
            for (int kk = 0; kk < 2; ++kk) {
                const int kx = kk << 6;
                bf16x8 bfr[4];
#pragma unroll
                for (int t = 0; t < 4; ++t)
                    bfr[t] = *(const bf16x8*)(cb + (boff[t] ^ kx));
#pragma unroll
                for (int mt = 0; mt < 4; ++mt) {
                    bf16x8 a = *(const bf16x8*)(xb + (aoff[mt] ^ kx));
#pragma unroll
                    for (int t = 0; t < 4; ++t)
                        acc[mt][t] = __builtin_amdgcn_mfma_f32_16x16x32_bf16(a, bfr[t], acc[mt][t], 0, 0, 0);
                }
            }
            // ---- step fence (skip after last dsb: epilogue runs first,
            // hiding the next kt's stage under ~2.5k cycles of VALU)
            if (dsb < 7) {
                asm volatile("s_waitcnt vmcnt(0)" ::: "memory");
                __builtin_amdgcn_s_barrier();
            }
        }

        // epilogue: proxy dist = c_norm - 2*S; running top-2 per (lane,row).
#pragma unroll
        for (int t = 0; t < 4; ++t) {
            const int cl  = kt * BN + wk * 64 + t * 16 + lr;
            const int col = kc0 + cl;
            const float cnv = cnl[cl];
#pragma unroll
            for (int mt = 0; mt < 4; ++mt)
#pragma unroll
                for (int r = 0; r < 4; ++r) {
                    float d = fmaf(-2.f, acc[mt][t][r], cnv);
                    float o1 = rd1[mt][r]; int oi1 = ri1[mt][r];
                    bool b1 = d < o1;
                    bool b2 = d < rd2[mt][r];
                    rd2[mt][r] = fminf(fmaxf(d, o1), rd2[mt][r]);   // v_med3_f32
                    ri2[mt][r] = b1 ? oi1 : (b2 ? col : ri2[mt][r]);
                    rd1[mt][r] = fminf(d, o1);
                    ri1[mt][r] = b1 ? col : oi1;
                }
        }
        // kt fence (also completes the first stage of kt+1's overlap window)
        asm volatile("s_waitcnt vmcnt(0)" ::: "memory");
        __builtin_amdgcn_s_barrier();
    }

    // Merge 16 lanes/row (each holding sorted top-2) -> sorted top-4 per (wk,row)
#pragma unroll
    for (int mt = 0; mt < 4; ++mt)
#pragma unroll
        for (int r = 0; r < 4; ++r) {
            float a0 = rd1[mt][r], a1 = rd2[mt][r], a2 = 1e30f, a3 = 1e30f;
            int   i0 = ri1[mt][r], i1 = ri2[mt][r], i2 = 0x7ffffff2, i3 = 0x7ffffff3;
#pragma unroll
            for (int s = 1; s < 16; s <<= 1) {
                float p0 = __shfl_xor(a0, s, 64), p1 = __shfl_xor(a1, s, 64);
                float p2 = __shfl_xor(a2, s, 64), p3 = __shfl_xor(a3, s, 64);
                int   q0 = __shfl_xor(i0, s, 64), q1 = __shfl_xor(i1, s, 64);
                int   q2 = __shfl_xor(i2, s, 64), q3 = __shfl_xor(i3, s, 64);
                float l0, l1, l2, l3; int m0, m1, m2, m3;
                lmin(a0, i0, p3, q3, l0, m0);
                lmin(a1, i1, p2, q2, l1, m1);
                lmin(a2, i2, p1, q1, l2, m2);
                lmin(a3, i3, p0, q0, l3, m3);
                ce(l0, m0, l2, m2); ce(l1, m1, l3, m3);
                ce(l0, m0, l1, m1); ce(l2, m2, l3, m3);
                a0 = l0; a1 = l1; a2 = l2; a3 = l3;
                i0 = m0; i1 = m1; i2 = m2; i3 = m3;
            }
            if (lr == 0) {
                const int rl = wm * 64 + mt * 16 + quad * 4 + r;
                sh_d[wk][rl][0] = a0; sh_i[wk][rl][0] = i0;
                sh_d[wk][rl][1] = a1; sh_i[wk][rl][1] = i1;
                sh_d[wk][rl][2] = a2; sh_i[wk][rl][2] = i2;
                sh_d[wk][rl][3] = a3; sh_i[wk][rl][3] = i3;
            }
        }
    __syncthreads();

    // Cross-wk merge: two sorted-4 lists -> this quarter's true top-4 per row.
    if (tid < BM) {
        float a0 = sh_d[0][tid][0], a1 = sh_d[0][tid][1];
        float a2 = sh_d[0][tid][2], a3 = sh_d[0][tid][3];
        int   i0 = sh_i[0][tid][0], i1 = sh_i[0][tid][1];
        int   i2 = sh_i[0][tid][2], i3 = sh_i[0][tid][3];
        float b0 = sh_d[1][tid][0], b1 = sh_d[1][tid][1];
        float b2 = sh_d[1][tid][2], b3 = sh_d[1][tid][3];
        int   j0 = sh_i[1][tid][0], j1 = sh_i[1][tid][1];
        int   j2 = sh_i[1][tid][2], j3 = sh_i[1][tid][3];
        float l0, l1, l2, l3; int m0, m1, m2, m3;
        lmin(a0, i0, b3, j3, l0, m0);
        lmin(a1, i1, b2, j2, l1, m1);
        lmin(a2, i2, b1, j1, l2, m2);
        lmin(a3, i3, b0, j0, l3, m3);
        ce(l0, m0, l2, m2); ce(l1, m1, l3, m3);
        ce(l0, m0, l1, m1); ce(l2, m2, l3, m3);
        float* cell = cand + ((size_t)(nbase + tid) * NQ + blockIdx.y) * 8;
        cell[0] = l0; cell[1] = (float)m0;
        cell[2] = l1; cell[3] = (float)m1;
        cell[4] = l2; cell[5] = (float)m2;
        cell[6] = l3; cell[7] = (float)m3;
    }
}

// ---------------- k2: fp64-exact refine over 16 candidates; idx + loss
// (+ fused x_q write when cand lives in d_ws, so no aliasing with x_q)
__global__ void __launch_bounds__(256) vq_refine(const float* __restrict__ x,
                                                 const float* __restrict__ cg,
                                                 const float* __restrict__ cand,
                                                 float* __restrict__ outp,
                                                 int write_xq) {
    __shared__ double ls[4];
    const int wave = threadIdx.x >> 6, lane = threadIdx.x & 63;
    const int n = blockIdx.x * 4 + wave;
    const float* cell = cand + (size_t)n * 32;

    const float* xr = x + (size_t)n * DIM + lane * 8;
    float4 xa = *(const float4*)xr;
    float4 xb = *(const float4*)(xr + 4);

    double bd = 1e300; int bi = 0x7fffffff;
    float4 va = xa, vb = xb;

#pragma unroll
    for (int batch = 0; batch < 2; ++batch) {
        int kid[8];
#pragma unroll
        for (int j = 0; j < 8; ++j) kid[j] = (int)cell[(batch * 8 + j) * 2 + 1];

        // prefetch the 8 candidate rows (breaks the serial load-latency chain)
        float4 ca[8], cb[8];
#pragma unroll
        for (int j = 0; j < 8; ++j) {
            const float* cr = cg + (size_t)kid[j] * DIM + lane * 8;
            ca[j] = *(const float4*)cr;
            cb[j] = *(const float4*)(cr + 4);
        }

#pragma unroll
        for (int j = 0; j < 8; ++j) {
            const int k = kid[j];
            double s = 0.0, t;
            t = (double)xa.x - (double)ca[j].x; s += t * t;
            t = (double)xa.y - (double)ca[j].y; s += t * t;
            t = (double)xa.z - (double)ca[j].z; s += t * t;
            t = (double)xa.w - (double)ca[j].w; s += t * t;
            t = (double)xb.x - (double)cb[j].x; s += t * t;
            t = (double)xb.y - (double)cb[j].y; s += t * t;
            t = (double)xb.z - (double)cb[j].z; s += t * t;
            t = (double)xb.w - (double)cb[j].w; s += t * t;
#pragma unroll
            for (int off = 32; off; off >>= 1) s += __shfl_down(s, off, 64);
            s = __shfl(s, 0, 64);
            bool w = (s < bd) || (s == bd && k < bi);
            bd = w ? s : bd;
            bi = w ? k : bi;
            va.x = w ? ca[j].x : va.x; va.y = w ? ca[j].y : va.y;
            va.z = w ? ca[j].z : va.z; va.w = w ? ca[j].w : va.w;
            vb.x = w ? cb[j].x : vb.x; vb.y = w ? cb[j].y : vb.y;
            vb.z = w ? cb[j].z : vb.z; vb.w = w ? cb[j].w : vb.w;
        }
    }
    if (write_xq) {
        float* row = outp + (size_t)n * DIM + lane * 8;
        *(float4*)row = va;
        *(float4*)(row + 4) = vb;
    }
    if (lane == 0) { outp[IDX_OFF + n] = (float)bi; ls[wave] = bd; }
    __syncthreads();
    if (threadIdx.x == 0)
        atomicAdd(outp + LOSS_OFF,
                  (float)((ls[0] + ls[1] + ls[2] + ls[3]) * (1.25 / 16777216.0)));
}

// ---------------- k3 (fallback only): gather x_q from final indices
__global__ void __launch_bounds__(256) vq_gather(const float* __restrict__ cg,
                                                 float* __restrict__ outp) {
    const int wave = threadIdx.x >> 6, lane = threadIdx.x & 63;
    const int n = blockIdx.x * 4 + wave;
    const int k = (int)outp[IDX_OFF + n];
    const float* cr = cg + (size_t)k * DIM + lane * 8;
    float4 a = *(const float4*)cr;
    float4 b = *(const float4*)(cr + 4);
    float* row = outp + (size_t)n * DIM + lane * 8;
    *(float4*)row = a;
    *(float4*)(row + 4) = b;
}

extern "C" void kernel_launch(void* const* d_in, const int* in_sizes, int n_in,
                              void* d_out, int out_size, void* d_ws, size_t ws_size,
                              hipStream_t stream) {
    const float* x   = (const float*)d_in[0];
    const float* cen = (const float*)d_in[1];
    float* out = (float*)d_out;

    unsigned short* xh  = (unsigned short*)((char*)d_out + XH_OFF_B);
    unsigned short* chp = (unsigned short*)((char*)d_out + CH_OFF_B);

    // Prefer workspace for cand+cnorm: lets refine write x_q directly (no
    // aliasing with the cand region). Fallback: old d_out layout + gather.
    const int fused = (d_ws != nullptr) && (ws_size >= (size_t)(CAND_BYTES + CN_BYTES));
    float* cand = fused ? (float*)d_ws
                        : (float*)((char*)d_out + CAND_OFF_B);
    float* cnp  = fused ? (float*)((char*)d_ws + CAND_BYTES)
                        : (float*)((char*)d_out + CN_OFF_B);

    hipMemsetAsync((void*)(out + LOSS_OFF), 0, sizeof(float), stream);
    convert_kernel<<<(N_ROWS + K_CENT) / 4, 256, 0, stream>>>(x, cen, xh, chp, cnp);
    dim3 g2(N_ROWS / BM, NQ);
    vq_main<<<g2, 256, 0, stream>>>(xh, chp, cnp, cand);
    vq_refine<<<N_ROWS / 4, 256, 0, stream>>>(x, cen, cand, out, fused);
    if (!fused) vq_gather<<<N_ROWS / 4, 256, 0, stream>>>(cen, out);
}

// Round 6
// 632.003 us; speedup vs baseline: 1.1355x; 1.1355x over previous
//
#include <hip/hip_runtime.h>
#include <hip/hip_bf16.h>

// Problem: x [32768,512] fp32, centroids [8192,512] fp32
#define N_ROWS 32768
#define DIM    512
#define K_CENT 8192

// Output (flat fp32): x_q [N*D] | loss [1] | indices-as-float [N]
#define LOSS_OFF 16777216u
#define IDX_OFF  16777217u

// Scratch carved from the x_q region of d_out (xh/ch always; cnorm/cand only
// when d_ws is too small for them):
#define XH_OFF_B   0u
#define CH_OFF_B   33554432u
#define CN_OFF_B   41943040u
#define CAND_OFF_B 41975808u

#define CAND_BYTES 2097152u
#define CN_BYTES   32768u

#define BM 128
#define BN 128
#define KHALF 4096           // columns per blockIdx.y half
#define NKT (KHALF / BN)     // 32
#define NH  2

typedef __bf16 bf16x8 __attribute__((ext_vector_type(8)));
typedef float  f32x4  __attribute__((ext_vector_type(4)));

__device__ __forceinline__ unsigned short f2bf(float f) {
    unsigned u = __float_as_uint(f);
    return (unsigned short)((u + 0x7fffu + ((u >> 16) & 1u)) >> 16);
}

// Async global->LDS, 16B per lane. LDS dest = wave-uniform base + lane*16;
// GLOBAL src is per-lane.
__device__ __forceinline__ void glds16(void* lds, const void* g) {
    __builtin_amdgcn_global_load_lds(
        (const __attribute__((address_space(1))) unsigned*)g,
        (__attribute__((address_space(3))) unsigned*)lds, 16, 0, 0);
}

// compare-exchange on (d,i) pairs, lexicographic
__device__ __forceinline__ void ce(float& da, int& ia, float& db, int& ib) {
    bool sw = (db < da) || (db == da && ib < ia);
    float td = sw ? db : da; int ti = sw ? ib : ia;
    float ud = sw ? da : db; int ui = sw ? ia : ib;
    da = td; ia = ti; db = ud; ib = ui;
}
__device__ __forceinline__ void lmin(float da, int ia, float db, int ib,
                                     float& od, int& oi) {
    bool sw = (db < da) || (db == da && ib < ia);
    od = sw ? db : da; oi = sw ? ib : ia;
}

// ---------------- k0: one-shot fp32 -> bf16(hi) conversion + c_norm
__global__ void __launch_bounds__(256) convert_kernel(const float* __restrict__ x,
                                                      const float* __restrict__ c,
                                                      unsigned short* __restrict__ xh,
                                                      unsigned short* __restrict__ ch,
                                                      float* __restrict__ cnp) {
    const int wave = threadIdx.x >> 6, lane = threadIdx.x & 63;
    const int gid = blockIdx.x * 4 + wave;
    if (gid < N_ROWS) {
        const float* p = x + (size_t)gid * DIM + lane * 8;
        float4 a = *(const float4*)p, b = *(const float4*)(p + 4);
        uint4 w;
        w.x = (unsigned)f2bf(a.x) | ((unsigned)f2bf(a.y) << 16);
        w.y = (unsigned)f2bf(a.z) | ((unsigned)f2bf(a.w) << 16);
        w.z = (unsigned)f2bf(b.x) | ((unsigned)f2bf(b.y) << 16);
        w.w = (unsigned)f2bf(b.z) | ((unsigned)f2bf(b.w) << 16);
        *(uint4*)(xh + (size_t)gid * DIM + lane * 8) = w;
    } else {
        const int cr = gid - N_ROWS;
        const float* p = c + (size_t)cr * DIM + lane * 8;
        float4 a = *(const float4*)p, b = *(const float4*)(p + 4);
        uint4 w;
        w.x = (unsigned)f2bf(a.x) | ((unsigned)f2bf(a.y) << 16);
        w.y = (unsigned)f2bf(a.z) | ((unsigned)f2bf(a.w) << 16);
        w.z = (unsigned)f2bf(b.x) | ((unsigned)f2bf(b.y) << 16);
        w.w = (unsigned)f2bf(b.z) | ((unsigned)f2bf(b.w) << 16);
        *(uint4*)(ch + (size_t)cr * DIM + lane * 8) = w;
        float s = a.x*a.x + a.y*a.y + a.z*a.z + a.w*a.w
                + b.x*b.x + b.y*b.y + b.z*b.z + b.w*b.w;
#pragma unroll
        for (int off = 32; off; off >>= 1) s += __shfl_down(s, off, 64);
        if (lane == 0) cnp[cr] = s;
    }
}

// ---------------- k1: bf16 MFMA proxy GEMM, ring-4 counted-vmcnt pipeline.
// grid (256, 2). Slot = 32-K tile (x[128][32] + c[128][32], 16 KB).
// Per step: vmcnt(8) [2 slots stay in flight] -> barrier -> issue slot s+3
// -> compute slot s. One barrier per 32-K; vmcnt never drained in the loop.
// LDS 16B-slot swizzle: phys = quad ^ ((lr>>1)&3); source pre-swizzled with
// the same involution ((lane&3)^((lane>>3)&3)) so glds16 dest stays linear.
__global__ void __launch_bounds__(256, 2) vq_main(const unsigned short* __restrict__ xh,
                                                  const unsigned short* __restrict__ ch,
                                                  const float* __restrict__ cnp,
                                                  float* __restrict__ cand) {
    __shared__ __align__(16) unsigned short xs[4 * 4096];  // 4 ring slots x 8 KB
    __shared__ __align__(16) unsigned short cs[4 * 4096];  // 4 ring slots x 8 KB
    __shared__ float sh_d[2][BM][4];                       // 4 KB
    __shared__ int   sh_i[2][BM][4];                       // 4 KB

    const int tid  = threadIdx.x;
    const int wave = tid >> 6, lane = tid & 63;
    const int wm   = wave >> 1, wk = wave & 1;
    const int lr   = lane & 15, quad = lane >> 4;
    const int nbase = blockIdx.x * BM;
    const int h     = blockIdx.y;
    const int kc0   = h * KHALF;

    // staging lane geometry: call g covers rows [wave*32+g*16, +16), lane ->
    // (row = g*16 + (lane>>2), phys slot = lane&3), source slot pre-swizzled.
    const int srow16 = lane >> 2;
    const int sswz   = (lane & 3) ^ ((lane >> 3) & 3);
    const unsigned short* xg0 = xh + (size_t)(nbase + wave * 32 + srow16) * DIM + sswz * 8;
    const unsigned short* xg1 = xg0 + (size_t)16 * DIM;
    const unsigned short* cg0 = ch + (size_t)(kc0 + wave * 32 + srow16) * DIM + sswz * 8;

    unsigned short* xw = xs + wave * 1024;   // + ring*4096 + g*512
    unsigned short* cw = cs + wave * 1024;

#define STAGE(ring, ktn, dd) do {                                          \
        unsigned short* xd_ = xw + (ring) * 4096;                          \
        unsigned short* cd_ = cw + (ring) * 4096;                          \
        const unsigned short* cgk_ = cg0 + (size_t)(ktn) * (BN * DIM) + (dd); \
        glds16(xd_,       xg0 + (dd));                                     \
        glds16(xd_ + 512, xg1 + (dd));                                     \
        glds16(cd_,       cgk_);                                           \
        glds16(cd_ + 512, cgk_ + 16 * DIM);                                \
    } while (0)

    // fragment read offsets (bytes within a ring slot), swizzled
    int aoff[4], boff[4];
#pragma unroll
    for (int t = 0; t < 4; ++t) {
        const int sw = (quad ^ ((lr >> 1) & 3)) << 4;
        aoff[t] = (wm * 64 + t * 16 + lr) * 64 + sw;
        boff[t] = (wk * 64 + t * 16 + lr) * 64 + sw;
    }

    float rd1[4][4], rd2[4][4];
    int   ri1[4][4], ri2[4][4];
#pragma unroll
    for (int mt = 0; mt < 4; ++mt)
#pragma unroll
        for (int r = 0; r < 4; ++r) {
            rd1[mt][r] = 1e30f; rd2[mt][r] = 1e30f;
            ri1[mt][r] = 0x7ffffff0; ri2[mt][r] = 0x7ffffff1;
        }

    // ---- prologue: stage slots 0..2, full drain once
    STAGE(0, 0, 0);
    STAGE(1, 0, 32);
    STAGE(2, 0, 64);
    asm volatile("s_waitcnt vmcnt(0)" ::: "memory");
    __builtin_amdgcn_s_barrier();

    for (int kt = 0; kt < NKT; ++kt) {
        const int kc = kc0 + kt * BN;
        // c_norm prefetch for this kt's epilogue (issued early; FIFO-older
        // than the slot loads staged below, so its wait can't drain them)
        float cnv[4];
#pragma unroll
        for (int t = 0; t < 4; ++t) cnv[t] = cnp[kc + wk * 64 + t * 16 + lr];

        f32x4 acc[4][4];
#pragma unroll
        for (int mt = 0; mt < 4; ++mt)
#pragma unroll
            for (int t = 0; t < 4; ++t)
                acc[mt][t] = (f32x4){0.f, 0.f, 0.f, 0.f};

#pragma unroll 4
        for (int j = 0; j < 16; ++j) {
            // slot s = kt*16 + j ready once at most 2 newer slots remain
            asm volatile("s_waitcnt vmcnt(8)" ::: "memory");
            __builtin_amdgcn_s_barrier();
            // issue slot s+3 (safe: all waves are past compute of s-1,
            // whose ring entry this overwrites)
            if (kt < NKT - 1 || j < 13) {
                const int jn = j + 3;
                STAGE(jn & 3, kt + (jn >> 4), (jn & 15) * 32);
            }
            // compute slot s from ring (j&3)
            const char* xb = (const char*)xs + (j & 3) * 8192;
            const char* cb = (const char*)cs + (j & 3) * 8192;
            bf16x8 bfr[4];
#pragma unroll
            for (int t = 0; t < 4; ++t)
                bfr[t] = *(const bf16x8*)(cb + boff[t]);
#pragma unroll
            for (int mt = 0; mt < 4; ++mt) {
                bf16x8 a = *(const bf16x8*)(xb + aoff[mt]);
#pragma unroll
                for (int t = 0; t < 4; ++t)
                    acc[mt][t] = __builtin_amdgcn_mfma_f32_16x16x32_bf16(a, bfr[t], acc[mt][t], 0, 0, 0);
            }
        }

        // epilogue: proxy dist = c_norm - 2*S; running top-2 per (lane,row).
        // Overlaps the (still in-flight) prefetch of the next kt's slots.
#pragma unroll
        for (int t = 0; t < 4; ++t) {
            const int col = kc + wk * 64 + t * 16 + lr;
#pragma unroll
            for (int mt = 0; mt < 4; ++mt)
#pragma unroll
                for (int r = 0; r < 4; ++r) {
                    float d = fmaf(-2.f, acc[mt][t][r], cnv[t]);
                    bool b1 = d < rd1[mt][r];
                    bool b2 = d < rd2[mt][r];
                    float o1 = rd1[mt][r]; int oi1 = ri1[mt][r];
                    rd2[mt][r] = b1 ? o1 : (b2 ? d : rd2[mt][r]);
                    ri2[mt][r] = b1 ? oi1 : (b2 ? col : ri2[mt][r]);
                    rd1[mt][r] = b1 ? d : o1;
                    ri1[mt][r] = b1 ? col : oi1;
                }
        }
    }
#undef STAGE

    // Merge 16 lanes/row (each holding sorted top-2) -> sorted top-4 per (wk,row)
#pragma unroll
    for (int mt = 0; mt < 4; ++mt)
#pragma unroll
        for (int r = 0; r < 4; ++r) {
            float a0 = rd1[mt][r], a1 = rd2[mt][r], a2 = 1e30f, a3 = 1e30f;
            int   i0 = ri1[mt][r], i1 = ri2[mt][r], i2 = 0x7ffffff2, i3 = 0x7ffffff3;
#pragma unroll
            for (int s = 1; s < 16; s <<= 1) {
                float p0 = __shfl_xor(a0, s, 64), p1 = __shfl_xor(a1, s, 64);
                float p2 = __shfl_xor(a2, s, 64), p3 = __shfl_xor(a3, s, 64);
                int   q0 = __shfl_xor(i0, s, 64), q1 = __shfl_xor(i1, s, 64);
                int   q2 = __shfl_xor(i2, s, 64), q3 = __shfl_xor(i3, s, 64);
                float l0, l1, l2, l3; int m0, m1, m2, m3;
                lmin(a0, i0, p3, q3, l0, m0);
                lmin(a1, i1, p2, q2, l1, m1);
                lmin(a2, i2, p1, q1, l2, m2);
                lmin(a3, i3, p0, q0, l3, m3);
                ce(l0, m0, l2, m2); ce(l1, m1, l3, m3);
                ce(l0, m0, l1, m1); ce(l2, m2, l3, m3);
                a0 = l0; a1 = l1; a2 = l2; a3 = l3;
                i0 = m0; i1 = m1; i2 = m2; i3 = m3;
            }
            if (lr == 0) {
                const int rl = wm * 64 + mt * 16 + quad * 4 + r;
                sh_d[wk][rl][0] = a0; sh_i[wk][rl][0] = i0;
                sh_d[wk][rl][1] = a1; sh_i[wk][rl][1] = i1;
                sh_d[wk][rl][2] = a2; sh_i[wk][rl][2] = i2;
                sh_d[wk][rl][3] = a3; sh_i[wk][rl][3] = i3;
            }
        }
    __syncthreads();

    // Cross-wk merge: two sorted-4 lists -> this half's true top-4 per row.
    if (tid < BM) {
        float a0 = sh_d[0][tid][0], a1 = sh_d[0][tid][1];
        float a2 = sh_d[0][tid][2], a3 = sh_d[0][tid][3];
        int   i0 = sh_i[0][tid][0], i1 = sh_i[0][tid][1];
        int   i2 = sh_i[0][tid][2], i3 = sh_i[0][tid][3];
        float b0 = sh_d[1][tid][0], b1 = sh_d[1][tid][1];
        float b2 = sh_d[1][tid][2], b3 = sh_d[1][tid][3];
        int   j0 = sh_i[1][tid][0], j1 = sh_i[1][tid][1];
        int   j2 = sh_i[1][tid][2], j3 = sh_i[1][tid][3];
        float l0, l1, l2, l3; int m0, m1, m2, m3;
        lmin(a0, i0, b3, j3, l0, m0);
        lmin(a1, i1, b2, j2, l1, m1);
        lmin(a2, i2, b1, j1, l2, m2);
        lmin(a3, i3, b0, j0, l3, m3);
        ce(l0, m0, l2, m2); ce(l1, m1, l3, m3);
        ce(l0, m0, l1, m1); ce(l2, m2, l3, m3);
        float* cell = cand + ((size_t)(nbase + tid) * NH + h) * 8;
        cell[0] = l0; cell[1] = (float)m0;
        cell[2] = l1; cell[3] = (float)m1;
        cell[4] = l2; cell[5] = (float)m2;
        cell[6] = l3; cell[7] = (float)m3;
    }
}

// ---------------- k2: fp64-exact refine over 8 candidates; idx + loss
// (+ fused x_q write when cand lives in d_ws, so no aliasing with x_q)
__global__ void __launch_bounds__(256) vq_refine(const float* __restrict__ x,
                                                 const float* __restrict__ cg,
                                                 const float* __restrict__ cand,
                                                 float* __restrict__ outp,
                                                 int write_xq) {
    __shared__ double ls[4];
    const int wave = threadIdx.x >> 6, lane = threadIdx.x & 63;
    const int n = blockIdx.x * 4 + wave;
    const float* cell = cand + (size_t)n * 16;
    int kid[8];
#pragma unroll
    for (int j = 0; j < 8; ++j) kid[j] = (int)cell[2 * j + 1];

    const float* xr = x + (size_t)n * DIM + lane * 8;
    float4 xa = *(const float4*)xr;
    float4 xb = *(const float4*)(xr + 4);

    // prefetch all 8 candidate rows (breaks the serial load-latency chain)
    float4 ca[8], cb[8];
#pragma unroll
    for (int j = 0; j < 8; ++j) {
        const float* cr = cg + (size_t)kid[j] * DIM + lane * 8;
        ca[j] = *(const float4*)cr;
        cb[j] = *(const float4*)(cr + 4);
    }

    double bd = 1e300; int bi = 0x7fffffff;
    float4 va = xa, vb = xb;
#pragma unroll
    for (int j = 0; j < 8; ++j) {
        const int k = kid[j];
        double s = 0.0, t;
        t = (double)xa.x - (double)ca[j].x; s += t * t;
        t = (double)xa.y - (double)ca[j].y; s += t * t;
        t = (double)xa.z - (double)ca[j].z; s += t * t;
        t = (double)xa.w - (double)ca[j].w; s += t * t;
        t = (double)xb.x - (double)cb[j].x; s += t * t;
        t = (double)xb.y - (double)cb[j].y; s += t * t;
        t = (double)xb.z - (double)cb[j].z; s += t * t;
        t = (double)xb.w - (double)cb[j].w; s += t * t;
#pragma unroll
        for (int off = 32; off; off >>= 1) s += __shfl_down(s, off, 64);
        s = __shfl(s, 0, 64);
        bool w = (s < bd) || (s == bd && k < bi);
        bd = w ? s : bd;
        bi = w ? k : bi;
        va.x = w ? ca[j].x : va.x; va.y = w ? ca[j].y : va.y;
        va.z = w ? ca[j].z : va.z; va.w = w ? ca[j].w : va.w;
        vb.x = w ? cb[j].x : vb.x; vb.y = w ? cb[j].y : vb.y;
        vb.z = w ? cb[j].z : vb.z; vb.w = w ? cb[j].w : vb.w;
    }
    if (write_xq) {
        float* row = outp + (size_t)n * DIM + lane * 8;
        *(float4*)row = va;
        *(float4*)(row + 4) = vb;
    }
    if (lane == 0) { outp[IDX_OFF + n] = (float)bi; ls[wave] = bd; }
    __syncthreads();
    if (threadIdx.x == 0)
        atomicAdd(outp + LOSS_OFF,
                  (float)((ls[0] + ls[1] + ls[2] + ls[3]) * (1.25 / 16777216.0)));
}

// ---------------- k3 (fallback only): gather x_q from final indices
__global__ void __launch_bounds__(256) vq_gather(const float* __restrict__ cg,
                                                 float* __restrict__ outp) {
    const int wave = threadIdx.x >> 6, lane = threadIdx.x & 63;
    const int n = blockIdx.x * 4 + wave;
    const int k = (int)outp[IDX_OFF + n];
    const float* cr = cg + (size_t)k * DIM + lane * 8;
    float4 a = *(const float4*)cr;
    float4 b = *(const float4*)(cr + 4);
    float* row = outp + (size_t)n * DIM + lane * 8;
    *(float4*)row = a;
    *(float4*)(row + 4) = b;
}

extern "C" void kernel_launch(void* const* d_in, const int* in_sizes, int n_in,
                              void* d_out, int out_size, void* d_ws, size_t ws_size,
                              hipStream_t stream) {
    const float* x   = (const float*)d_in[0];
    const float* cen = (const float*)d_in[1];
    float* out = (float*)d_out;

    unsigned short* xh  = (unsigned short*)((char*)d_out + XH_OFF_B);
    unsigned short* chp = (unsigned short*)((char*)d_out + CH_OFF_B);

    // Prefer workspace for cand+cnorm: lets refine write x_q directly (no
    // aliasing with the cand region). Fallback: old d_out layout + gather.
    const int fused = (d_ws != nullptr) && (ws_size >= (size_t)(CAND_BYTES + CN_BYTES));
    float* cand = fused ? (float*)d_ws
                        : (float*)((char*)d_out + CAND_OFF_B);
    float* cnp  = fused ? (float*)((char*)d_ws + CAND_BYTES)
                        : (float*)((char*)d_out + CN_OFF_B);

    hipMemsetAsync((void*)(out + LOSS_OFF), 0, sizeof(float), stream);
    convert_kernel<<<(N_ROWS + K_CENT) / 4, 256, 0, stream>>>(x, cen, xh, chp, cnp);
    dim3 g2(N_ROWS / BM, NH);
    vq_main<<<g2, 256, 0, stream>>>(xh, chp, cnp, cand);
    vq_refine<<<N_ROWS / 4, 256, 0, stream>>>(x, cen, cand, out, fused);
    if (!fused) vq_gather<<<N_ROWS / 4, 256, 0, stream>>>(cen, out);
}